// Round 5
// baseline (702.593 us; speedup 1.0000x reference)
//
#include <hip/hip_runtime.h>

#define TT   512
#define HD   18
#define CH   4                 /* batches per block */
#define UPR  (CH*HD*2)         /* 144 active units per role */
#define SLOT 192               /* role slot = 3 waves */
#define NTH  (2*SLOT)          /* 384 threads */
#define SEGU 12                /* dwords per segment row: 9 data + 3 pad */

typedef _Float16 v2h __attribute__((ext_vector_type(2)));

__device__ __forceinline__ float fsig(float x){ return __builtin_amdgcn_rcpf(1.0f + __expf(-x)); }

__global__ __launch_bounds__(NTH, 6) void lstm2_deep(
    const float* __restrict__ x,
    const float* __restrict__ wih0, const float* __restrict__ whh0,
    const float* __restrict__ bih0, const float* __restrict__ bhh0,
    const float* __restrict__ wih1, const float* __restrict__ whh1,
    const float* __restrict__ bih1, const float* __restrict__ bhh1,
    float* __restrict__ out)
{
    // f16 segments (9 dwords data each): x ring (4-deep), h1/h2 double-buffered
    __shared__ uint xr [4][CH][SEGU];
    __shared__ uint h1s[2][CH][SEGU];
    __shared__ uint h2s[2][CH][SEGU];

    const int  tid   = threadIdx.x;
    const bool role2 = (tid >= SLOT);              // wave-uniform
    const int  u     = role2 ? tid - SLOT : tid;
    const bool act   = (u < UPR);
    const int  b     = u / 36;
    const int  r     = u % 36;
    const int  h     = r >> 1;
    const int  gp    = r & 1;                      // 0:(i,f)  1:(g,o)
    const size_t gb  = (size_t)blockIdx.x * CH + b;

    // ---- per-lane f16 weights for TWO gate rows (36 VGPRs) ----
    v2h W0[18], W1[18];
    float bias0 = 0.f, bias1 = 0.f;
    if (act) {
        const float* wih = role2 ? wih1 : wih0;
        const float* whh = role2 ? whh1 : whh0;
        const float* bi  = role2 ? bih1 : bih0;
        const float* bh  = role2 ? bhh1 : bhh0;
        const int r0 = (gp ? 2*HD : 0) + h;
        const int r1 = (gp ? 3*HD : HD) + h;
        #pragma unroll
        for (int j = 0; j < 9; ++j) {
            W0[j]   = v2h{(_Float16)wih[r0*HD + 2*j], (_Float16)wih[r0*HD + 2*j+1]};
            W0[9+j] = v2h{(_Float16)whh[r0*HD + 2*j], (_Float16)whh[r0*HD + 2*j+1]};
            W1[j]   = v2h{(_Float16)wih[r1*HD + 2*j], (_Float16)wih[r1*HD + 2*j+1]};
            W1[9+j] = v2h{(_Float16)whh[r1*HD + 2*j], (_Float16)whh[r1*HD + 2*j+1]};
        }
        bias0 = bi[r0] + bh[r0];
        bias1 = bi[r1] + bh[r1];
    }

    const float* xb = x   + gb*TT*HD;
    float*       ob = out + gb*TT*HD;

    // ---- init: fill x ring t=0..2, issue x[3]; zero h1[-1], h2[-1] ----
    float xhold = 0.f;
    if (act) {
        if (!role2) {
            if (gp) {
                _Float16* f;
                f = (_Float16*)&xr[0][b][0]; f[h] = (_Float16)xb[0*HD + h];
                f = (_Float16*)&xr[1][b][0]; f[h] = (_Float16)xb[1*HD + h];
                f = (_Float16*)&xr[2][b][0]; f[h] = (_Float16)xb[2*HD + h];
                xhold = xb[3*HD + h];
            } else {
                ((_Float16*)&h1s[1][b][0])[h] = (_Float16)0.f;   // h1[-1]
            }
        } else if (!gp) {
            ((_Float16*)&h2s[0][b][0])[h] = (_Float16)0.f;       // h2[-1]
        }
    }
    __syncthreads();

    float c = 0.f;

    for (int n = 0; n <= TT; ++n) {
        const bool run = act && (role2 ? (n >= 1) : (n < TT));

        if (run) {
            const uint* Ap;
            const uint* Bp;
            if (!role2) {
                Ap = &xr [n & 3][b][0];
                Bp = &h1s[(n + 1) & 1][b][0];
            } else {
                Ap = &h1s[(n + 1) & 1][b][0];
                Bp = &h2s[(n + 1) & 1][b][0];
            }

            // deep x staging: store x[n+3] (loaded at iter n-1), load x[n+4]
            if (!role2 && gp) {
                if (n + 3 < TT)
                    ((_Float16*)&xr[(n + 3) & 3][b][0])[h] = (_Float16)xhold;
                if (n + 4 < TT)
                    xhold = xb[(size_t)(n + 4) * HD + h];
            }

            float a0a = bias0, a1a = bias1, a0b = 0.f, a1b = 0.f;
            #pragma unroll
            for (int j = 0; j < 9; ++j) {
                const v2h vA = __builtin_bit_cast(v2h, Ap[j]);
                a0a = __builtin_amdgcn_fdot2(vA, W0[j], a0a, false);
                a1a = __builtin_amdgcn_fdot2(vA, W1[j], a1a, false);
            }
            #pragma unroll
            for (int j = 0; j < 9; ++j) {
                const v2h vB = __builtin_bit_cast(v2h, Bp[j]);
                a0b = __builtin_amdgcn_fdot2(vB, W0[9 + j], a0b, false);
                a1b = __builtin_amdgcn_fdot2(vB, W1[9 + j], a1b, false);
            }
            const float a0 = a0a + a0b, a1 = a1a + a1b;

            // gp0 owns (i,f); gp1 owns (g,o); exchange via intra-pair shuffle
            const float s0 = fsig(gp ? 2.f * a0 : a0);
            const float u0 = gp ? 2.f * s0 - 1.f : s0;
            const float u1 = fsig(a1);
            const float v0 = __shfl_xor(u0, 1, 64);
            const float v1 = __shfl_xor(u1, 1, 64);
            const float gi = gp ? v0 : u0;
            const float gf = gp ? v1 : u1;
            const float gg = gp ? u0 : v0;
            const float go = gp ? u1 : v1;
            c = gf * c + gi * gg;
            const float th = 2.f * fsig(2.f * c) - 1.f;
            const float hv = go * th;

            if (!role2) {
                if (!gp) ((_Float16*)&h1s[n & 1][b][0])[h] = (_Float16)hv;
            } else {
                if (!gp) ((_Float16*)&h2s[n & 1][b][0])[h] = (_Float16)hv;
                else     ob[(size_t)(n - 1) * HD + h] = hv;
            }
        }
        __syncthreads();
    }
}

extern "C" void kernel_launch(void* const* d_in, const int* in_sizes, int n_in,
                              void* d_out, int out_size, void* d_ws, size_t ws_size,
                              hipStream_t stream) {
    const float* x    = (const float*)d_in[0];
    const float* wih0 = (const float*)d_in[1];
    const float* whh0 = (const float*)d_in[2];
    const float* bih0 = (const float*)d_in[3];
    const float* bhh0 = (const float*)d_in[4];
    const float* wih1 = (const float*)d_in[5];
    const float* whh1 = (const float*)d_in[6];
    const float* bih1 = (const float*)d_in[7];
    const float* bhh1 = (const float*)d_in[8];
    float* out = (float*)d_out;

    lstm2_deep<<<dim3(4096 / CH), dim3(NTH), 0, stream>>>(
        x, wih0, whh0, bih0, bhh0, wih1, whh1, bih1, bhh1, out);
}

// Round 6
// 278.307 us; speedup vs baseline: 2.5245x; 2.5245x over previous
//
#include <hip/hip_runtime.h>

#define TT   512
#define HD   18
#define NB   16          /* batches per block */
#define NTH  256         /* 4 waves */
#define RS   68          /* LDS row stride in halves (136B: 8B-aligned, odd dwords) */

typedef _Float16 v8h __attribute__((ext_vector_type(8)));
typedef float    v4f __attribute__((ext_vector_type(4)));

__device__ __forceinline__ float fsig(float x) {
    return __builtin_amdgcn_rcpf(1.0f + __expf(-x));
}

// LDS rows (per buffer, per batch): k[0..17]=input (x or h1), k[18..35]=own h,
// k[36]=1.0 (bias column), k[37..67]=0.
// Buffers: SH[0..3] = layer-1 ring (x 3-ahead, h1 1-ahead); SH[4..5] = layer-2 dbuf.

template<int NT>
__device__ __forceinline__ void run_wave(
    int tbase, int isl1, int pfmode, int lane,
    const float* __restrict__ x,
    const float* __restrict__ wih, const float* __restrict__ whh,
    const float* __restrict__ bi,  const float* __restrict__ bh,
    float* __restrict__ out,
    _Float16 (*SH)[NB][RS], size_t b0)
{
    const int rl = lane & 15;       // batch column
    const int lg = lane >> 4;       // k-group / h-subrow

    // ---- A fragments: W'[row=4h+g][k] , k: 0-17 wih, 18-35 whh, 36 bias ----
    v8h Af[NT][2];
    int hh[NT];
    #pragma unroll
    for (int i = 0; i < NT; ++i) {
        const int row = 16 * (tbase + i) + rl;
        const int h = row >> 2, g = row & 3;
        const int r = g * HD + h;
        #pragma unroll
        for (int s = 0; s < 2; ++s) {
            v8h a;
            #pragma unroll
            for (int j = 0; j < 8; ++j) {
                const int k = 8 * lg + j + 32 * s;
                float v = 0.f;
                if (h < HD) {
                    if (k < HD)            v = wih[r * HD + k];
                    else if (k < 2 * HD)   v = whh[r * HD + (k - HD)];
                    else if (k == 2 * HD)  v = bi[r] + bh[r];
                }
                a[j] = (_Float16)v;
            }
            Af[i][s] = a;
        }
        hh[i] = 4 * (tbase + i) + lg;   // this lane's h for tile i (C-layout)
    }

    // output pointers (used by layer-2 waves)
    float* op[NT];
    #pragma unroll
    for (int i = 0; i < NT; ++i)
        op[i] = out + (b0 + rl) * (size_t)TT * HD + hh[i];

    // ---- x-prefetch lane assignments (fixed elements) ----
    int pb[3] = {0,0,0}, pk[3] = {0,0,0}; bool pv[3] = {false,false,false};
    float xpf[3] = {0.f, 0.f, 0.f};
    if (pfmode) {
        int ee[3];
        ee[0] = (pfmode == 1) ? lane       : 128 + lane;
        ee[1] = (pfmode == 1) ? 64 + lane  : 192 + lane;
        ee[2] = (pfmode == 1) ? 256 + lane : 999;
        #pragma unroll
        for (int j = 0; j < 3; ++j) {
            pv[j] = ee[j] < NB * HD;
            pb[j] = pv[j] ? ee[j] / HD : 0;
            pk[j] = pv[j] ? ee[j] % HD : 0;
            if (pv[j])   // preload x[3]
                xpf[j] = x[(b0 + pb[j]) * (size_t)TT * HD + 3 * HD + pk[j]];
        }
    }

    float cst[NT];
    #pragma unroll
    for (int i = 0; i < NT; ++i) cst[i] = 0.f;

    for (int n = 0; n <= TT; ++n) {
        const bool active = isl1 ? (n < TT) : (n >= 1);
        if (active) {
            const int bufi = isl1 ? (n & 3) : (4 + (n & 1));
            const _Float16* rowp = &SH[bufi][rl][0];
            v8h Bf[2];
            #pragma unroll
            for (int s = 0; s < 2; ++s) {
                union { uint2 u[2]; v8h v; } cv;
                cv.u[0] = *(const uint2*)(rowp + 8 * lg + 32 * s);
                cv.u[1] = *(const uint2*)(rowp + 8 * lg + 32 * s + 4);
                Bf[s] = cv.v;
            }
            const int wb1 = (n + 1) & 3;        // L1 ring slot for h1[n]
            const int wb2 = 4 + ((n + 1) & 1);  // L2 dbuf slot for next iter
            #pragma unroll
            for (int i = 0; i < NT; ++i) {
                v4f acc = {0.f, 0.f, 0.f, 0.f};
                acc = __builtin_amdgcn_mfma_f32_16x16x32_f16(Af[i][0], Bf[0], acc, 0, 0, 0);
                acc = __builtin_amdgcn_mfma_f32_16x16x32_f16(Af[i][1], Bf[1], acc, 0, 0, 0);
                const float gi = fsig(acc[0]);
                const float gf = fsig(acc[1]);
                const float gg = 2.f * fsig(2.f * acc[2]) - 1.f;   // tanh
                const float go = fsig(acc[3]);
                cst[i] = gf * cst[i] + gi * gg;
                const float th = 2.f * fsig(2.f * cst[i]) - 1.f;
                const float hv = go * th;
                const _Float16 h16 = (_Float16)hv;
                if (hh[i] < HD) {
                    if (isl1) {
                        SH[wb1][rl][HD + hh[i]] = h16;   // h1 -> own recurrence
                        SH[wb2][rl][hh[i]]      = h16;   // h1 -> layer-2 input
                    } else {
                        SH[wb2][rl][HD + hh[i]] = h16;   // h2 -> own recurrence
                        op[i][(size_t)(n - 1) * HD] = hv;  // final output h2[n-1]
                    }
                }
            }
        }
        // ---- deep x staging: store x[n+3] (held), load x[n+4] ----
        if (pfmode) {
            if (n + 3 < TT) {
                const int xb = (n + 3) & 3;
                #pragma unroll
                for (int j = 0; j < 3; ++j)
                    if (pv[j]) SH[xb][pb[j]][pk[j]] = (_Float16)xpf[j];
            }
            if (n + 4 < TT) {
                #pragma unroll
                for (int j = 0; j < 3; ++j)
                    if (pv[j]) xpf[j] = x[(b0 + pb[j]) * (size_t)TT * HD
                                          + (size_t)(n + 4) * HD + pk[j]];
            }
        }
        __syncthreads();
    }
}

__global__ __launch_bounds__(NTH) void lstm2_mfma(
    const float* __restrict__ x,
    const float* __restrict__ wih0, const float* __restrict__ whh0,
    const float* __restrict__ bih0, const float* __restrict__ bhh0,
    const float* __restrict__ wih1, const float* __restrict__ whh1,
    const float* __restrict__ bih1, const float* __restrict__ bhh1,
    float* __restrict__ out)
{
    __shared__ __align__(16) _Float16 SH[6][NB][RS];

    const int tid  = threadIdx.x;
    const int wid  = tid >> 6;
    const int lane = tid & 63;
    const size_t b0 = (size_t)blockIdx.x * NB;

    // ---- init: zero everything, set bias columns, fill x[0..2] ----
    {
        uint* shw = (uint*)&SH[0][0][0];            // 6*16*68/2 = 3264 dwords
        for (int i = tid; i < 6 * NB * RS / 2; i += NTH) shw[i] = 0u;
        __syncthreads();
        for (int i = tid; i < 6 * NB; i += NTH)
            SH[i / NB][i % NB][2 * HD] = (_Float16)1.0f;
        for (int i = tid; i < 3 * NB * HD; i += NTH) {
            const int t = i / (NB * HD), r2 = i % (NB * HD);
            const int b = r2 / HD, k = r2 % HD;
            SH[t][b][k] = (_Float16)x[(b0 + b) * (size_t)TT * HD + t * HD + k];
        }
        __syncthreads();
    }

    if      (wid == 0) run_wave<3>(0, 1, 0, lane, x, wih0, whh0, bih0, bhh0, out, SH, b0);
    else if (wid == 1) run_wave<2>(3, 1, 1, lane, x, wih0, whh0, bih0, bhh0, out, SH, b0);
    else if (wid == 2) run_wave<3>(0, 0, 0, lane, x, wih1, whh1, bih1, bhh1, out, SH, b0);
    else               run_wave<2>(3, 0, 2, lane, x, wih1, whh1, bih1, bhh1, out, SH, b0);
}

extern "C" void kernel_launch(void* const* d_in, const int* in_sizes, int n_in,
                              void* d_out, int out_size, void* d_ws, size_t ws_size,
                              hipStream_t stream) {
    const float* x    = (const float*)d_in[0];
    const float* wih0 = (const float*)d_in[1];
    const float* whh0 = (const float*)d_in[2];
    const float* bih0 = (const float*)d_in[3];
    const float* bhh0 = (const float*)d_in[4];
    const float* wih1 = (const float*)d_in[5];
    const float* whh1 = (const float*)d_in[6];
    const float* bih1 = (const float*)d_in[7];
    const float* bhh1 = (const float*)d_in[8];
    float* out = (float*)d_out;
    (void)d_ws; (void)ws_size; (void)in_sizes; (void)n_in; (void)out_size;

    lstm2_mfma<<<dim3(4096 / NB), dim3(NTH), 0, stream>>>(
        x, wih0, whh0, bih0, bhh0, wih1, whh1, bih1, bhh1, out);
}